// Round 13
// baseline (99.329 us; speedup 1.0000x reference)
//
#include <hip/hip_runtime.h>

typedef __bf16 bf16;
typedef __attribute__((ext_vector_type(8))) __bf16 bf16x8;
typedef __attribute__((ext_vector_type(4))) __bf16 bf16x4;
typedef __attribute__((ext_vector_type(4))) float f32x4;

static constexpr int ROWS = 16384;   // BS*N_AGENTS

// ---------------- workspace layout (bf16 elements) ----------------
// Fragment-major swizzle: element (n,k) of an [N,K] matrix lives at
//   ((n/16)*(K/32) + k/32)*512 + lane*8 + (k&7),  lane = (n&15) | (((k>>3)&3)<<4)
static constexpr size_t OFF_WFC1 = 0;        // [256,128]
static constexpr size_t OFF_WRX  = 32768;    // [256,256] Wih rows 0-255
static constexpr size_t OFF_WZX  = 98304;    // [256,256] Wih rows 256-511
static constexpr size_t OFF_WNI  = 163840;   // [256,256] Wih rows 512-767
static constexpr size_t OFF_WRH  = 229376;   // [256,256] Whh rows 0-255
static constexpr size_t OFF_WZH  = 294912;   // [256,256] Whh rows 256-511
static constexpr size_t OFF_WNH  = 360448;   // [256,256] Whh rows 512-767
static constexpr size_t OFF_WQ   = 425984;   // [64,256]
static constexpr size_t OFF_WKV  = 442368;   // [320,256]: kw n16 0-3, vw n16 4-19
static constexpr size_t OFF_F2AH = 524288;   // [256,256] f2aw cols 0-255
static constexpr size_t OFF_F2AM = 589824;   // [256,256] f2aw cols 256-511
static constexpr size_t OFF_WF2B = 655360;   // [16,256]
static constexpr size_t OFF_INSW = 659456;   // [16384,128] 'in', frag-major
static constexpr size_t OFF_MSGK = 2756608;  // [16384,64]  bf16 row-major
static constexpr size_t OFF_MSGV = 3805184;  // [16384,256] bf16 row-major

// ---------------- swizzle (f32 row-major -> bf16 fragment-major) ----------------
struct SwzSeg { const float* src; bf16* dst; int items; int k8s; int k32; int ld; };
struct SwzArgs { SwzSeg seg[14]; int count; };

__global__ __launch_bounds__(256) void swz_k(SwzArgs a) {
    const int tid = blockIdx.x * 256 + threadIdx.x;
    const int stride = gridDim.x * 256;
    for (int s = 0; s < a.count; ++s) {
        const float* __restrict__ src = a.seg[s].src;
        bf16* __restrict__ dst = a.seg[s].dst;
        const int items = a.seg[s].items, k8s = a.seg[s].k8s;
        const int k32c = a.seg[s].k32, ld = a.seg[s].ld;
        for (int i = tid; i < items; i += stride) {
            const int n = i >> k8s, kb = i & ((1 << k8s) - 1);
            const int k0 = kb << 3;
            const int lane = (n & 15) | ((kb & 3) << 4);
            const size_t off = ((size_t)((n >> 4) * k32c + (kb >> 2)) * 64 + lane) * 8;
            const float* p = src + (size_t)n * ld + k0;
            float4 f0 = *(const float4*)p;
            float4 f1 = *(const float4*)(p + 4);
            bf16x8 o = { (bf16)f0.x, (bf16)f0.y, (bf16)f0.z, (bf16)f0.w,
                         (bf16)f1.x, (bf16)f1.y, (bf16)f1.z, (bf16)f1.w };
            *(bf16x8*)(dst + off) = o;
        }
    }
}

// frag-major LDS index for a [32,256] tile (2 rowgrps x 8 k32)
__device__ __forceinline__ int fm32(int row, int k) {
    return ((row >> 4) * 8 + (k >> 5)) * 512 +
           (((row & 15) | (((k >> 3) & 3) << 4)) << 3) + (k & 7);
}

// ---------------- MFMA helpers ----------------
// A row-major LDS (lda stride), B frag-major global (pre-offset) — for msgkv
template<int FM, int FN, int K32>
__device__ __forceinline__ void mm_rm(f32x4 (&acc)[FM][FN],
    const bf16* __restrict__ sA, int lda,
    const bf16* __restrict__ W, int lane)
{
    const int lr = lane & 15, lk = (lane >> 4) << 3;
    #pragma unroll
    for (int k32 = 0; k32 < K32; ++k32) {
        bf16x8 a[FM], b[FN];
        #pragma unroll
        for (int j = 0; j < FN; ++j)
            b[j] = *(const bf16x8*)(W + ((size_t)(j * K32 + k32) * 64 + lane) * 8);
        #pragma unroll
        for (int i = 0; i < FM; ++i)
            a[i] = *(const bf16x8*)&sA[(i * 16 + lr) * lda + k32 * 32 + lk];
        #pragma unroll
        for (int i = 0; i < FM; ++i)
            #pragma unroll
            for (int j = 0; j < FN; ++j)
                acc[i][j] = __builtin_amdgcn_mfma_f32_16x16x32_bf16(a[i], b[j], acc[i][j], 0, 0, 0);
    }
}

// A frag-major LDS (pre-offset to rowgrp0), B frag-major global (pre-offset)
template<int FM, int FN, int K32>
__device__ __forceinline__ void mm_fm(f32x4 (&acc)[FM][FN],
    const bf16* __restrict__ sA, const bf16* __restrict__ W, int lane)
{
    #pragma unroll
    for (int k32 = 0; k32 < K32; ++k32) {
        bf16x8 a[FM], b[FN];
        #pragma unroll
        for (int j = 0; j < FN; ++j)
            b[j] = *(const bf16x8*)(W + ((size_t)(j * K32 + k32) * 64 + lane) * 8);
        #pragma unroll
        for (int i = 0; i < FM; ++i)
            a[i] = *(const bf16x8*)&sA[((i * K32 + k32) * 64 + lane) * 8];
        #pragma unroll
        for (int i = 0; i < FM; ++i)
            #pragma unroll
            for (int j = 0; j < FN; ++j)
                acc[i][j] = __builtin_amdgcn_mfma_f32_16x16x32_bf16(a[i], b[j], acc[i][j], 0, 0, 0);
    }
}

__device__ __forceinline__ float sigmf(float x) { return 1.f / (1.f + __expf(-x)); }
__device__ __forceinline__ float tanh_fast(float x) {
    x = fminf(fmaxf(x, -15.f), 15.f);
    float e2 = __expf(2.f * x);
    return (e2 - 1.f) / (e2 + 1.f);
}

// ---------------- msg K/V projection: BM=64, N=320 (R3 form) ----------------
__global__ __launch_bounds__(512)
void msgkv_k(const float* __restrict__ msg_f, const bf16* __restrict__ Wkv,
             bf16* __restrict__ msgk, bf16* __restrict__ msgv)
{
    __shared__ bf16 sA[64 * 264];
    const int tid = threadIdx.x;
    const int wave = tid >> 6, lane = tid & 63;
    const int wm = wave >> 2, wn = wave & 3;
    const int m0 = blockIdx.x * 64;
    const int lr = lane & 15, l4 = (lane >> 4) << 2;

    for (int c = tid; c < 4096; c += 512) {
        int r = c >> 6, cg = (c & 63) << 2;
        float4 f = *(const float4*)(msg_f + (size_t)(m0 + r) * 256 + cg);
        bf16x4 o = { (bf16)f.x, (bf16)f.y, (bf16)f.z, (bf16)f.w };
        *(bf16x4*)&sA[r * 264 + cg] = o;
    }
    __syncthreads();

    f32x4 acc[2][5] = {};
    mm_rm<2, 5, 8>(acc, sA + wm * 32 * 264, 264, Wkv + (size_t)(wn * 5) * 8 * 512, lane);

    #pragma unroll
    for (int i = 0; i < 2; ++i)
        #pragma unroll
        for (int j = 0; j < 5; ++j) {
            const int col = wn * 80 + j * 16 + lr;
            #pragma unroll
            for (int rr = 0; rr < 4; ++rr) {
                const size_t row = m0 + wm * 32 + i * 16 + l4 + rr;
                if (col < 64) msgk[row * 64 + col] = (bf16)acc[i][j][rr];
                else          msgv[row * 256 + col - 64] = (bf16)acc[i][j][rr];
            }
        }
}

// ---------------- mega: HALF-batch per block (32 Q-rows), 8 waves, 2 blocks/CU ----
// LDS: sHf (hidden -> m_agg, fm) 16K | sXf (X -> Y, fm) 16K | sMf (h, fm) 16K
//      sK [64,72] 9K | sQ [32,64] 4K | sIdx 1K  => ~62 KB -> 2 blocks/CU.
__global__ __launch_bounds__(512, 4)
void mega_k(const bf16* __restrict__ insw, const float* __restrict__ hid_f,
            const int* __restrict__ topk,
            const bf16* __restrict__ Wfc1, const float* __restrict__ fc1_b,
            const bf16* __restrict__ WrX, const bf16* __restrict__ WrH,
            const bf16* __restrict__ WzX, const bf16* __restrict__ WzH,
            const bf16* __restrict__ Wni, const bf16* __restrict__ Wnh,
            const float* __restrict__ b_ih, const float* __restrict__ b_hh,
            const bf16* __restrict__ Wq, const float* __restrict__ q_b,
            const bf16* __restrict__ msgk, const bf16* __restrict__ msgv,
            const float* __restrict__ v_bias,
            const bf16* __restrict__ f2aH, const bf16* __restrict__ f2aM,
            const float* __restrict__ f2a_b,
            const bf16* __restrict__ Wf2b, const float* __restrict__ f2b_b,
            float* __restrict__ h_out, float* __restrict__ magg_out,
            float* __restrict__ q_out)
{
    __shared__ bf16 sHf[8192];
    __shared__ bf16 sXf[8192];
    __shared__ bf16 sMf[8192];
    __shared__ bf16 sK[64 * 72];
    __shared__ bf16 sQ[32 * 64];
    __shared__ int  sIdx[256];
    const int tid = threadIdx.x;
    const int wave = tid >> 6, lane = tid & 63;
    const int batch = blockIdx.x >> 1, half = blockIdx.x & 1;
    const int b64 = batch * 64;
    const int r0 = b64 + half * 32;          // first Q row of this block
    const int lr = lane & 15, l4 = (lane >> 4) << 2;

    // --- stage hidden [32,256] f32->bf16 (fm), K [64,64] bf16, topk
    #pragma unroll
    for (int c = tid; c < 2048; c += 512) {
        int r = c >> 6, cg = (c & 63) << 2;
        float4 f = *(const float4*)(hid_f + (size_t)(r0 + r) * 256 + cg);
        bf16x4 oh = { (bf16)f.x, (bf16)f.y, (bf16)f.z, (bf16)f.w };
        *(bf16x4*)&sHf[fm32(r, cg)] = oh;
    }
    {
        int row = tid >> 3, cg = (tid & 7) << 3;
        *(bf16x8*)&sK[row * 72 + cg] = *(const bf16x8*)(msgk + (size_t)(b64 + row) * 64 + cg);
    }
    if (tid < 256) sIdx[tid] = topk[(size_t)r0 * 8 + tid];

    // --- fc1: X = relu(in @ fc1w^T + b) -> sXf. Wave tile [32,32].
    {
        f32x4 fa[2][2] = {};
        #pragma unroll
        for (int k32 = 0; k32 < 4; ++k32) {
            bf16x8 a[2], b[2];
            #pragma unroll
            for (int g = 0; g < 2; ++g)
                a[g] = *(const bf16x8*)(insw + ((size_t)(((r0 >> 4) + g) * 4 + k32) * 64 + lane) * 8);
            #pragma unroll
            for (int j = 0; j < 2; ++j)
                b[j] = *(const bf16x8*)(Wfc1 + ((size_t)((wave * 2 + j) * 4 + k32) * 64 + lane) * 8);
            #pragma unroll
            for (int g = 0; g < 2; ++g)
                #pragma unroll
                for (int j = 0; j < 2; ++j)
                    fa[g][j] = __builtin_amdgcn_mfma_f32_16x16x32_bf16(a[g], b[j], fa[g][j], 0, 0, 0);
        }
        #pragma unroll
        for (int g = 0; g < 2; ++g)
            #pragma unroll
            for (int j = 0; j < 2; ++j) {
                const int col = wave * 32 + j * 16 + lr;
                const float bv = fc1_b[col];
                #pragma unroll
                for (int rr = 0; rr < 4; ++rr)
                    sXf[fm32(g * 16 + l4 + rr, col)] = (bf16)fmaxf(fa[g][j][rr] + bv, 0.f);
            }
    }
    __syncthreads();   // B1: sXf, sHf, sK, sIdx visible

    // --- GRU gates: 2 col-passes, wave tile [32,16], acc = 32 AGPR (room to pipeline)
    #pragma unroll 1
    for (int p = 0; p < 2; ++p) {
        const size_t nb = (size_t)(p * 8 + wave) * 8 * 512 + lane * 8;
        f32x4 rg[2] = {}, zg[2] = {}, ng[2] = {}, hg[2] = {};
        #pragma unroll
        for (int k32 = 0; k32 < 8; ++k32) {
            const size_t bo = (size_t)k32 * 512;
            bf16x8 brx = *(const bf16x8*)(WrX + nb + bo);
            bf16x8 bzx = *(const bf16x8*)(WzX + nb + bo);
            bf16x8 bni = *(const bf16x8*)(Wni + nb + bo);
            bf16x8 brh = *(const bf16x8*)(WrH + nb + bo);
            bf16x8 bzh = *(const bf16x8*)(WzH + nb + bo);
            bf16x8 bnh = *(const bf16x8*)(Wnh + nb + bo);
            bf16x8 ax0 = *(const bf16x8*)&sXf[((size_t)k32 * 64 + lane) * 8];
            bf16x8 ax1 = *(const bf16x8*)&sXf[((size_t)(8 + k32) * 64 + lane) * 8];
            bf16x8 ah0 = *(const bf16x8*)&sHf[((size_t)k32 * 64 + lane) * 8];
            bf16x8 ah1 = *(const bf16x8*)&sHf[((size_t)(8 + k32) * 64 + lane) * 8];
            __builtin_amdgcn_s_setprio(1);
            rg[0] = __builtin_amdgcn_mfma_f32_16x16x32_bf16(ax0, brx, rg[0], 0, 0, 0);
            rg[1] = __builtin_amdgcn_mfma_f32_16x16x32_bf16(ax1, brx, rg[1], 0, 0, 0);
            zg[0] = __builtin_amdgcn_mfma_f32_16x16x32_bf16(ax0, bzx, zg[0], 0, 0, 0);
            zg[1] = __builtin_amdgcn_mfma_f32_16x16x32_bf16(ax1, bzx, zg[1], 0, 0, 0);
            ng[0] = __builtin_amdgcn_mfma_f32_16x16x32_bf16(ax0, bni, ng[0], 0, 0, 0);
            ng[1] = __builtin_amdgcn_mfma_f32_16x16x32_bf16(ax1, bni, ng[1], 0, 0, 0);
            rg[0] = __builtin_amdgcn_mfma_f32_16x16x32_bf16(ah0, brh, rg[0], 0, 0, 0);
            rg[1] = __builtin_amdgcn_mfma_f32_16x16x32_bf16(ah1, brh, rg[1], 0, 0, 0);
            zg[0] = __builtin_amdgcn_mfma_f32_16x16x32_bf16(ah0, bzh, zg[0], 0, 0, 0);
            zg[1] = __builtin_amdgcn_mfma_f32_16x16x32_bf16(ah1, bzh, zg[1], 0, 0, 0);
            hg[0] = __builtin_amdgcn_mfma_f32_16x16x32_bf16(ah0, bnh, hg[0], 0, 0, 0);
            hg[1] = __builtin_amdgcn_mfma_f32_16x16x32_bf16(ah1, bnh, hg[1], 0, 0, 0);
            __builtin_amdgcn_s_setprio(0);
        }
        // epilogue for this col-pass: h -> sMf (sHf stays old hidden for pass 1)
        const int col = p * 128 + wave * 16 + lr;
        const float br = b_ih[col] + b_hh[col];
        const float bz = b_ih[256 + col] + b_hh[256 + col];
        const float bi = b_ih[512 + col], bh = b_hh[512 + col];
        #pragma unroll
        for (int i = 0; i < 2; ++i)
            #pragma unroll
            for (int rr = 0; rr < 4; ++rr) {
                const int row = i * 16 + l4 + rr;
                const float rv = sigmf(rg[i][rr] + br);
                const float zv = sigmf(zg[i][rr] + bz);
                const float nn = tanh_fast((ng[i][rr] + bi) + rv * (hg[i][rr] + bh));
                const float hd = (float)sHf[fm32(row, col)];
                const float h = (1.f - zv) * nn + zv * hd;
                sMf[fm32(row, col)] = (bf16)h;
            }
    }
    __syncthreads();   // B2: sMf(h) complete; gate reads of sXf/sHf done

    // --- q-proj: q = h @ qw^T + q_b -> sQ. Wave tile [16,16] (2 rowgrp x 4 colgrp).
    {
        f32x4 qa[1][1] = {};
        mm_fm<1, 1, 8>(qa, sMf + (size_t)(wave >> 2) * 8 * 512,
                       Wq + (size_t)(wave & 3) * 8 * 512, lane);
        const int col = (wave & 3) * 16 + lr;
        const float bv = q_b[col];
        #pragma unroll
        for (int rr = 0; rr < 4; ++rr)
            sQ[((wave >> 2) * 16 + l4 + rr) * 64 + col] = (bf16)(qa[0][0][rr] + bv);
    }
    // --- h_out: coalesced f32 stream from sMf (bf16-rounded h; err << thr)
    #pragma unroll
    for (int c = tid; c < 2048; c += 512) {
        int r = c >> 6, cg = (c & 63) << 2;
        bf16x4 hv = *(const bf16x4*)&sMf[fm32(r, cg)];
        float4 o = { (float)hv[0], (float)hv[1], (float)hv[2], (float)hv[3] };
        *(float4*)(h_out + (size_t)(r0 + r) * 256 + cg) = o;
    }
    __syncthreads();   // B3: sQ visible

    // --- attention: wave handles agents wave*4..+3 (local 0..31); V gathered from L2.
    const int kk = lane >> 3, dg = lane & 7;
    #pragma unroll
    for (int uu = 0; uu < 4; ++uu) {
        const int u = wave * 4 + uu;
        const int rowk = sIdx[u * 8 + kk];      // batch-local agent id 0..63
        bf16x8 q8 = *(const bf16x8*)&sQ[u * 64 + dg * 8];
        bf16x8 k8 = *(const bf16x8*)&sK[rowk * 72 + dg * 8];
        float s = 0.f;
        #pragma unroll
        for (int t = 0; t < 8; ++t) s += (float)q8[t] * (float)k8[t];
        s += __shfl_xor(s, 1); s += __shfl_xor(s, 2); s += __shfl_xor(s, 4);
        float logit = s * 0.125f;
        float mx = logit;
        mx = fmaxf(mx, __shfl_xor(mx, 8));
        mx = fmaxf(mx, __shfl_xor(mx, 16));
        mx = fmaxf(mx, __shfl_xor(mx, 32));
        float e = __expf(logit - mx);
        float den = e;
        den += __shfl_xor(den, 8); den += __shfl_xor(den, 16); den += __shfl_xor(den, 32);
        const float wv = e / den;
        float a0 = 0.f, a1 = 0.f, a2 = 0.f, a3 = 0.f;
        #pragma unroll
        for (int k = 0; k < 8; ++k) {
            float wk = __shfl(wv, k * 8);
            int   rk = __shfl(rowk, k * 8);
            bf16x4 v = *(const bf16x4*)(msgv + (size_t)(b64 + rk) * 256 + lane * 4);
            a0 += wk * (float)v[0]; a1 += wk * (float)v[1];
            a2 += wk * (float)v[2]; a3 += wk * (float)v[3];
        }
        float4 vb = *(const float4*)(v_bias + lane * 4);
        a0 += vb.x; a1 += vb.y; a2 += vb.z; a3 += vb.w;
        float4 res = { a0, a1, a2, a3 };
        *(float4*)(magg_out + (size_t)(r0 + u) * 256 + lane * 4) = res;
        bf16x4 rb = { (bf16)a0, (bf16)a1, (bf16)a2, (bf16)a3 };
        *(bf16x4*)&sHf[fm32(u, lane * 4)] = rb;   // m_agg overwrites dead hidden
    }
    __syncthreads();   // B4: m_agg visible

    // --- fc2a: y = relu(h @ f2aH^T + m_agg @ f2aM^T + b) -> sXf (Y). Tile [32,32].
    {
        f32x4 ya[2][2] = {};
        mm_fm<2, 2, 8>(ya, sMf, f2aH + (size_t)(wave * 2) * 8 * 512, lane);
        mm_fm<2, 2, 8>(ya, sHf, f2aM + (size_t)(wave * 2) * 8 * 512, lane);
        #pragma unroll
        for (int i = 0; i < 2; ++i)
            #pragma unroll
            for (int j = 0; j < 2; ++j) {
                const int col = wave * 32 + j * 16 + lr;
                const float bv = f2a_b[col];
                #pragma unroll
                for (int rr = 0; rr < 4; ++rr)
                    sXf[fm32(i * 16 + l4 + rr, col)] = (bf16)fmaxf(ya[i][j][rr] + bv, 0.f);
            }
    }
    __syncthreads();   // B5: Y visible

    // --- fc2b: q_out = y @ f2bw^T + b (waves 0-1, [16,16] tiles)
    if (wave < 2) {
        f32x4 acc[1][1] = {};
        mm_fm<1, 1, 8>(acc, sXf + (size_t)wave * 8 * 512, Wf2b, lane);
        const float bv = f2b_b[lr];
        #pragma unroll
        for (int rr = 0; rr < 4; ++rr)
            q_out[(size_t)(r0 + wave * 16 + l4 + rr) * 16 + lr] = acc[0][0][rr] + bv;
    }
}

// ---------------- launch ----------------
extern "C" void kernel_launch(void* const* d_in, const int* in_sizes, int n_in,
                              void* d_out, int out_size, void* d_ws, size_t ws_size,
                              hipStream_t stream)
{
    const float* in_f   = (const float*)d_in[0];
    const float* hid_f  = (const float*)d_in[1];
    const float* msg_f  = (const float*)d_in[2];
    const int*   topk   = (const int*)d_in[3];
    const float* fc1w_f = (const float*)d_in[4];
    const float* fc1_b  = (const float*)d_in[5];
    const float* wih_f  = (const float*)d_in[6];
    const float* b_ih   = (const float*)d_in[7];
    const float* whh_f  = (const float*)d_in[8];
    const float* b_hh   = (const float*)d_in[9];
    const float* qw_f   = (const float*)d_in[10];
    const float* q_b    = (const float*)d_in[11];
    const float* kw_f   = (const float*)d_in[12];
    // d_in[13] = k_b: softmax-invariant, dropped.
    const float* vw_f   = (const float*)d_in[14];
    const float* v_b    = (const float*)d_in[15];
    const float* f2aw_f = (const float*)d_in[16];
    const float* f2a_b  = (const float*)d_in[17];
    const float* f2bw_f = (const float*)d_in[18];
    const float* f2b_b  = (const float*)d_in[19];

    bf16* ws = (bf16*)d_ws;
    bf16* Wfc1 = ws + OFF_WFC1;
    bf16* WrX  = ws + OFF_WRX;
    bf16* WzX  = ws + OFF_WZX;
    bf16* Wni  = ws + OFF_WNI;
    bf16* WrH  = ws + OFF_WRH;
    bf16* WzH  = ws + OFF_WZH;
    bf16* Wnh  = ws + OFF_WNH;
    bf16* Wq   = ws + OFF_WQ;
    bf16* Wkv  = ws + OFF_WKV;
    bf16* f2aH = ws + OFF_F2AH;
    bf16* f2aM = ws + OFF_F2AM;
    bf16* Wf2b = ws + OFF_WF2B;
    bf16* insw = ws + OFF_INSW;
    bf16* msgk = ws + OFF_MSGK;
    bf16* msgv = ws + OFF_MSGV;

    float* q_out    = (float*)d_out;                 // [16384,16]
    float* h_out    = q_out + (size_t)ROWS * 16;     // [16384,256]
    float* magg_out = h_out + (size_t)ROWS * 256;    // [16384,256]

    // 1) swizzle weights + 'in' activations to fragment-major bf16
    SwzArgs sa{};
    int s = 0;
    auto add = [&](const float* src, bf16* dst, int N, int K, int ld) {
        sa.seg[s].src = src; sa.seg[s].dst = dst;
        sa.seg[s].items = N * (K >> 3);
        sa.seg[s].k8s = (K == 128) ? 4 : 5;
        sa.seg[s].k32 = K >> 5;
        sa.seg[s].ld = ld; ++s;
    };
    add(fc1w_f,          Wfc1, 256, 128, 128);
    add(wih_f,           WrX,  256, 256, 256);
    add(wih_f +  65536,  WzX,  256, 256, 256);
    add(wih_f + 131072,  Wni,  256, 256, 256);
    add(whh_f,           WrH,  256, 256, 256);
    add(whh_f +  65536,  WzH,  256, 256, 256);
    add(whh_f + 131072,  Wnh,  256, 256, 256);
    add(qw_f,            Wq,    64, 256, 256);
    add(kw_f,            Wkv,   64, 256, 256);
    add(vw_f,            Wkv + 16384, 256, 256, 256);
    add(f2aw_f,          f2aH, 256, 256, 512);
    add(f2aw_f + 256,    f2aM, 256, 256, 512);
    add(f2bw_f,          Wf2b,  16, 256, 256);
    add(in_f,            insw, 16384, 128, 128);
    sa.count = s;
    swz_k<<<512, 256, 0, stream>>>(sa);

    // 2) msg K/V projections (row-parallel, full GPU)
    msgkv_k<<<256, 512, 0, stream>>>(msg_f, Wkv, msgk, msgv);

    // 3) half-batch megakernel: 512 blocks x 512 thr, 2 blocks/CU
    mega_k<<<512, 512, 0, stream>>>(insw, hid_f, topk,
                                    Wfc1, fc1_b, WrX, WrH, WzX, WzH, Wni, Wnh,
                                    b_ih, b_hh, Wq, q_b, msgk, msgv, v_b,
                                    f2aH, f2aM, f2a_b, Wf2b, f2b_b,
                                    h_out, magg_out, q_out);
}

// Round 14
// 56.307 us; speedup vs baseline: 1.7641x; 1.7641x over previous
//
#include <hip/hip_runtime.h>

typedef __bf16 bf16;
typedef __attribute__((ext_vector_type(8))) __bf16 bf16x8;
typedef __attribute__((ext_vector_type(4))) __bf16 bf16x4;
typedef __attribute__((ext_vector_type(4))) float f32x4;

static constexpr int ROWS = 16384;   // BS*N_AGENTS

// ---------------- workspace layout (bf16 elements) ----------------
// Fragment-major swizzle: element (n,k) of an [N,K] matrix lives at
//   ((n/16)*(K/32) + k/32)*512 + lane*8 + (k&7),  lane = (n&15) | (((k>>3)&3)<<4)
static constexpr size_t OFF_WFC1 = 0;        // [256,128]
static constexpr size_t OFF_WRX  = 32768;    // [256,256] Wih rows 0-255
static constexpr size_t OFF_WZX  = 98304;    // [256,256] Wih rows 256-511
static constexpr size_t OFF_WNI  = 163840;   // [256,256] Wih rows 512-767
static constexpr size_t OFF_WRH  = 229376;   // [256,256] Whh rows 0-255
static constexpr size_t OFF_WZH  = 294912;   // [256,256] Whh rows 256-511
static constexpr size_t OFF_WNH  = 360448;   // [256,256] Whh rows 512-767
static constexpr size_t OFF_WQ   = 425984;   // [64,256]
static constexpr size_t OFF_WKV  = 442368;   // [320,256]: kw n16 0-3, vw n16 4-19
static constexpr size_t OFF_F2AH = 524288;   // [256,256] f2aw cols 0-255
static constexpr size_t OFF_F2AM = 589824;   // [256,256] f2aw cols 256-511
static constexpr size_t OFF_WF2B = 655360;   // [16,256]
static constexpr size_t OFF_INSW = 659456;   // [16384,128] 'in' activations, frag-major

// ---------------- swizzle (f32 row-major -> bf16 fragment-major) ----------------
struct SwzSeg { const float* src; bf16* dst; int items; int k8s; int k32; int ld; };
struct SwzArgs { SwzSeg seg[14]; int count; };

__global__ __launch_bounds__(256) void swz_k(SwzArgs a) {
    const int tid = blockIdx.x * 256 + threadIdx.x;
    const int stride = gridDim.x * 256;
    for (int s = 0; s < a.count; ++s) {
        const float* __restrict__ src = a.seg[s].src;
        bf16* __restrict__ dst = a.seg[s].dst;
        const int items = a.seg[s].items, k8s = a.seg[s].k8s;
        const int k32c = a.seg[s].k32, ld = a.seg[s].ld;
        for (int i = tid; i < items; i += stride) {
            const int n = i >> k8s, kb = i & ((1 << k8s) - 1);
            const int k0 = kb << 3;
            const int lane = (n & 15) | ((kb & 3) << 4);
            const size_t off = ((size_t)((n >> 4) * k32c + (kb >> 2)) * 64 + lane) * 8;
            const float* p = src + (size_t)n * ld + k0;
            float4 f0 = *(const float4*)p;
            float4 f1 = *(const float4*)(p + 4);
            bf16x8 o = { (bf16)f0.x, (bf16)f0.y, (bf16)f0.z, (bf16)f0.w,
                         (bf16)f1.x, (bf16)f1.y, (bf16)f1.z, (bf16)f1.w };
            *(bf16x8*)(dst + off) = o;
        }
    }
}

// ---------------- MFMA helpers ----------------
// A from row-major LDS, B from fragment-major global (pre-offset to wave n16 base)
template<int FM, int FN, int K32>
__device__ __forceinline__ void mm_swz(f32x4 (&acc)[FM][FN],
    const bf16* __restrict__ sA, int lda,
    const bf16* __restrict__ W, int lane)
{
    const int lr = lane & 15, lk = (lane >> 4) << 3;
    #pragma unroll
    for (int k32 = 0; k32 < K32; ++k32) {
        bf16x8 a[FM], b[FN];
        #pragma unroll
        for (int j = 0; j < FN; ++j)
            b[j] = *(const bf16x8*)(W + ((size_t)(j * K32 + k32) * 64 + lane) * 8);
        #pragma unroll
        for (int i = 0; i < FM; ++i)
            a[i] = *(const bf16x8*)&sA[(i * 16 + lr) * lda + k32 * 32 + lk];
        #pragma unroll
        for (int i = 0; i < FM; ++i)
            #pragma unroll
            for (int j = 0; j < FN; ++j)
                acc[i][j] = __builtin_amdgcn_mfma_f32_16x16x32_bf16(a[i], b[j], acc[i][j], 0, 0, 0);
    }
}

// A and B both fragment-major global (pre-offset)
template<int FM, int FN, int K32>
__device__ __forceinline__ void mm_gg(f32x4 (&acc)[FM][FN],
    const bf16* __restrict__ A, const bf16* __restrict__ W, int lane)
{
    #pragma unroll
    for (int k32 = 0; k32 < K32; ++k32) {
        bf16x8 a[FM], b[FN];
        #pragma unroll
        for (int i = 0; i < FM; ++i)
            a[i] = *(const bf16x8*)(A + ((size_t)(i * K32 + k32) * 64 + lane) * 8);
        #pragma unroll
        for (int j = 0; j < FN; ++j)
            b[j] = *(const bf16x8*)(W + ((size_t)(j * K32 + k32) * 64 + lane) * 8);
        #pragma unroll
        for (int i = 0; i < FM; ++i)
            #pragma unroll
            for (int j = 0; j < FN; ++j)
                acc[i][j] = __builtin_amdgcn_mfma_f32_16x16x32_bf16(a[i], b[j], acc[i][j], 0, 0, 0);
    }
}

__device__ __forceinline__ float sigmf(float x) { return 1.f / (1.f + __expf(-x)); }
__device__ __forceinline__ float tanh_fast(float x) {
    x = fminf(fmaxf(x, -15.f), 15.f);
    float e2 = __expf(2.f * x);
    return (e2 - 1.f) / (e2 + 1.f);
}

// ---------------- megakernel: one block per batch, 16 waves (1024 thr) ----------------
// Best verified structure (R7/R11, 56.5 us): 1 block/CU keeps the 1.37 MB weight
// set L2-resident per phase; 64 AGPR acc + 6 B-streams exactly fills the 128-reg
// budget (zero spill). All latency-hiding perturbations of this structure were
// measured net-negative (R8-R13).
__global__ __launch_bounds__(1024)
void mega_k(const bf16* __restrict__ insw, const float* __restrict__ hid_f,
            const float* __restrict__ msg_f, const int* __restrict__ topk,
            const bf16* __restrict__ Wfc1, const float* __restrict__ fc1_b,
            const bf16* __restrict__ WrX, const bf16* __restrict__ WrH,
            const bf16* __restrict__ WzX, const bf16* __restrict__ WzH,
            const bf16* __restrict__ Wni, const bf16* __restrict__ Wnh,
            const float* __restrict__ b_ih, const float* __restrict__ b_hh,
            const bf16* __restrict__ Wq, const float* __restrict__ q_b,
            const bf16* __restrict__ Wkv, const float* __restrict__ v_bias,
            const bf16* __restrict__ f2aH, const bf16* __restrict__ f2aM,
            const float* __restrict__ f2a_b,
            const bf16* __restrict__ Wf2b, const float* __restrict__ f2b_b,
            float* __restrict__ h_out, float* __restrict__ magg_out,
            float* __restrict__ q_out)
{
    __shared__ bf16 sH[64 * 264];   // old hidden -> m_agg
    __shared__ bf16 sB[64 * 264];   // X -> V
    __shared__ bf16 sG[64 * 264];   // msg -> Y
    __shared__ bf16 sM[64 * 264];   // new h
    __shared__ bf16 sQ[64 * 72];
    __shared__ bf16 sK[64 * 72];
    __shared__ int  sIdx[512];
    const int tid = threadIdx.x;
    const int wave = tid >> 6, lane = tid & 63;
    const int b64 = blockIdx.x * 64;
    const int lr = lane & 15, l4 = (lane >> 4) << 2, lk = (lane >> 4) << 3;

    // --- stage hidden + msg [64,256] f32 -> bf16
    #pragma unroll
    for (int c = tid; c < 4096; c += 1024) {
        int r = c >> 6, cg = (c & 63) << 2;
        float4 f = *(const float4*)(hid_f + (size_t)(b64 + r) * 256 + cg);
        float4 g = *(const float4*)(msg_f + (size_t)(b64 + r) * 256 + cg);
        bf16x4 oh = { (bf16)f.x, (bf16)f.y, (bf16)f.z, (bf16)f.w };
        bf16x4 og = { (bf16)g.x, (bf16)g.y, (bf16)g.z, (bf16)g.w };
        *(bf16x4*)&sH[r * 264 + cg] = oh;
        *(bf16x4*)&sG[r * 264 + cg] = og;
    }
    if (tid < 512) sIdx[tid] = topk[(size_t)blockIdx.x * 512 + tid];

    // --- fc1: X = relu(in @ fc1w^T + b) -> sB. [16,64] tile per wave; A,B global.
    {
        f32x4 fa[1][4] = {};
        mm_gg<1, 4, 4>(fa, insw + (size_t)(blockIdx.x * 4 + (wave & 3)) * 4 * 512,
                       Wfc1 + (size_t)((wave >> 2) * 4) * 4 * 512, lane);
        #pragma unroll
        for (int j = 0; j < 4; ++j) {
            const int col = (wave >> 2) * 64 + j * 16 + lr;
            const float bv = fc1_b[col];
            #pragma unroll
            for (int rr = 0; rr < 4; ++rr)
                sB[((wave & 3) * 16 + l4 + rr) * 264 + col] = (bf16)fmaxf(fa[0][j][rr] + bv, 0.f);
        }
    }
    __syncthreads();   // B1: sB(X), sH, sG visible

    // --- GRU gates: fused 6-stream k-loop, wave tile [64,16] at col16 = wave.
    f32x4 rg[4] = {}, zg[4] = {}, ng[4] = {}, hg[4] = {};
    {
        const size_t nb = (size_t)wave * 8 * 512;
        const bf16 *pRX = WrX + nb, *pZX = WzX + nb, *pNI = Wni + nb;
        const bf16 *pRH = WrH + nb, *pZH = WzH + nb, *pNH = Wnh + nb;
        #pragma unroll
        for (int k32 = 0; k32 < 8; ++k32) {
            const size_t bo = (size_t)k32 * 512 + lane * 8;
            bf16x8 brx = *(const bf16x8*)(pRX + bo);
            bf16x8 bzx = *(const bf16x8*)(pZX + bo);
            bf16x8 bni = *(const bf16x8*)(pNI + bo);
            bf16x8 brh = *(const bf16x8*)(pRH + bo);
            bf16x8 bzh = *(const bf16x8*)(pZH + bo);
            bf16x8 bnh = *(const bf16x8*)(pNH + bo);
            __builtin_amdgcn_s_setprio(1);
            #pragma unroll
            for (int i = 0; i < 4; ++i) {
                bf16x8 ax = *(const bf16x8*)&sB[(i * 16 + lr) * 264 + k32 * 32 + lk];
                rg[i] = __builtin_amdgcn_mfma_f32_16x16x32_bf16(ax, brx, rg[i], 0, 0, 0);
                zg[i] = __builtin_amdgcn_mfma_f32_16x16x32_bf16(ax, bzx, zg[i], 0, 0, 0);
                ng[i] = __builtin_amdgcn_mfma_f32_16x16x32_bf16(ax, bni, ng[i], 0, 0, 0);
            }
            #pragma unroll
            for (int i = 0; i < 4; ++i) {
                bf16x8 ah = *(const bf16x8*)&sH[(i * 16 + lr) * 264 + k32 * 32 + lk];
                rg[i] = __builtin_amdgcn_mfma_f32_16x16x32_bf16(ah, brh, rg[i], 0, 0, 0);
                zg[i] = __builtin_amdgcn_mfma_f32_16x16x32_bf16(ah, bzh, zg[i], 0, 0, 0);
                hg[i] = __builtin_amdgcn_mfma_f32_16x16x32_bf16(ah, bnh, hg[i], 0, 0, 0);
            }
            __builtin_amdgcn_s_setprio(0);
        }
    }
    // --- GRU epilogue: h -> sM (bf16) only. h_out streamed coalesced later.
    {
        const int col = wave * 16 + lr;
        const float br = b_ih[col] + b_hh[col];
        const float bz = b_ih[256 + col] + b_hh[256 + col];
        const float bi = b_ih[512 + col], bh = b_hh[512 + col];
        #pragma unroll
        for (int i = 0; i < 4; ++i)
            #pragma unroll
            for (int rr = 0; rr < 4; ++rr) {
                const int row = i * 16 + l4 + rr;
                const float rv = sigmf(rg[i][rr] + br);
                const float zv = sigmf(zg[i][rr] + bz);
                const float nn = tanh_fast((ng[i][rr] + bi) + rv * (hg[i][rr] + bh));
                const float hd = (float)sH[row * 264 + col];
                const float h = (1.f - zv) * nn + zv * hd;
                sM[row * 264 + col] = (bf16)h;
            }
    }
    __syncthreads();   // B2: sM(h) visible; sB/sH gate reads complete

    // --- kv-proj: [K|V] = msg @ Wkv^T -> sK / sB(V). 20 n16 over 16 waves.
    if (wave < 4) {
        f32x4 a[4][2] = {};
        mm_swz<4, 2, 8>(a, sG, 264, Wkv + (size_t)(wave * 2) * 8 * 512, lane);
        #pragma unroll
        for (int i = 0; i < 4; ++i)
            #pragma unroll
            for (int j = 0; j < 2; ++j) {
                const int col = (wave * 2 + j) * 16 + lr;
                #pragma unroll
                for (int rr = 0; rr < 4; ++rr) {
                    const int row = i * 16 + l4 + rr;
                    if (col < 64) sK[row * 72 + col] = (bf16)a[i][j][rr];
                    else          sB[row * 264 + col - 64] = (bf16)a[i][j][rr];
                }
            }
    } else {
        f32x4 a[4][1] = {};
        mm_swz<4, 1, 8>(a, sG, 264, Wkv + (size_t)(4 + wave) * 8 * 512, lane);
        const int col = (4 + wave) * 16 + lr;   // >= 128, always V
        #pragma unroll
        for (int i = 0; i < 4; ++i)
            #pragma unroll
            for (int rr = 0; rr < 4; ++rr)
                sB[(i * 16 + l4 + rr) * 264 + col - 64] = (bf16)a[i][0][rr];
    }
    // --- q-proj: q = h @ qw^T + q_b -> sQ. [16,16] tile per wave.
    {
        f32x4 qa[1][1] = {};
        mm_swz<1, 1, 8>(qa, sM + (wave & 3) * 16 * 264, 264,
                        Wq + (size_t)(wave >> 2) * 8 * 512, lane);
        const int col = (wave >> 2) * 16 + lr;
        const float bv = q_b[col];
        #pragma unroll
        for (int rr = 0; rr < 4; ++rr)
            sQ[((wave & 3) * 16 + l4 + rr) * 72 + col] = (bf16)(qa[0][0][rr] + bv);
    }
    // --- h_out: coalesced f32 stream from sM (bf16-rounded h; err ~4e-3 << thr)
    #pragma unroll
    for (int u = 0; u < 4; ++u) {
        int c = tid + u * 1024;
        int r = c >> 6, cg = (c & 63) << 2;
        bf16x4 hv = *(const bf16x4*)&sM[r * 264 + cg];
        float4 o = { (float)hv[0], (float)hv[1], (float)hv[2], (float)hv[3] };
        *(float4*)(h_out + (size_t)(b64 + r) * 256 + cg) = o;
    }
    __syncthreads();   // B3

    // --- attention: wave handles agents wave*4 .. wave*4+3; m_agg -> sH
    const int kk = lane >> 3, dg = lane & 7;
    #pragma unroll
    for (int uu = 0; uu < 4; ++uu) {
        const int u = wave * 4 + uu;
        const int rowk = sIdx[u * 8 + kk];
        bf16x8 q8 = *(const bf16x8*)&sQ[u * 72 + dg * 8];
        bf16x8 k8 = *(const bf16x8*)&sK[rowk * 72 + dg * 8];
        float s = 0.f;
        #pragma unroll
        for (int t = 0; t < 8; ++t) s += (float)q8[t] * (float)k8[t];
        s += __shfl_xor(s, 1); s += __shfl_xor(s, 2); s += __shfl_xor(s, 4);
        float logit = s * 0.125f;
        float mx = logit;
        mx = fmaxf(mx, __shfl_xor(mx, 8));
        mx = fmaxf(mx, __shfl_xor(mx, 16));
        mx = fmaxf(mx, __shfl_xor(mx, 32));
        float e = __expf(logit - mx);
        float den = e;
        den += __shfl_xor(den, 8); den += __shfl_xor(den, 16); den += __shfl_xor(den, 32);
        const float wv = e / den;
        float a0 = 0.f, a1 = 0.f, a2 = 0.f, a3 = 0.f;
        #pragma unroll
        for (int k = 0; k < 8; ++k) {
            float wk = __shfl(wv, k * 8);
            int   rk = __shfl(rowk, k * 8);
            bf16x4 v = *(const bf16x4*)&sB[rk * 264 + lane * 4];
            a0 += wk * (float)v[0]; a1 += wk * (float)v[1];
            a2 += wk * (float)v[2]; a3 += wk * (float)v[3];
        }
        float4 vb = *(const float4*)(v_bias + lane * 4);
        a0 += vb.x; a1 += vb.y; a2 += vb.z; a3 += vb.w;
        float4 res = { a0, a1, a2, a3 };
        *(float4*)(magg_out + (size_t)(b64 + u) * 256 + lane * 4) = res;
        bf16x4 rb = { (bf16)a0, (bf16)a1, (bf16)a2, (bf16)a3 };
        *(bf16x4*)&sH[u * 264 + lane * 4] = rb;
    }
    __syncthreads();   // B4

    // --- fc2a: y = relu(h @ f2aH^T + m_agg @ f2aM^T + b) -> sG. Tile [64,16],
    //     fused 2-stream with depth-1 prefetch + setprio.
    {
        const size_t nb = (size_t)wave * 8 * 512;
        f32x4 ya[4] = {};
        const bf16* pH = f2aH + nb;
        const bf16* pM = f2aM + nb;
        const int lo = lane * 8;
        bf16x8 cH = *(const bf16x8*)(pH + lo);
        bf16x8 cM = *(const bf16x8*)(pM + lo);
        #pragma unroll
        for (int k = 0; k < 8; ++k) {
            bf16x8 nH, nM;
            if (k < 7) {
                nH = *(const bf16x8*)(pH + (k + 1) * 512 + lo);
                nM = *(const bf16x8*)(pM + (k + 1) * 512 + lo);
            }
            __builtin_amdgcn_s_setprio(1);
            #pragma unroll
            for (int i = 0; i < 4; ++i) {
                bf16x8 aH = *(const bf16x8*)&sM[(i * 16 + lr) * 264 + k * 32 + lk];
                ya[i] = __builtin_amdgcn_mfma_f32_16x16x32_bf16(aH, cH, ya[i], 0, 0, 0);
            }
            #pragma unroll
            for (int i = 0; i < 4; ++i) {
                bf16x8 aM = *(const bf16x8*)&sH[(i * 16 + lr) * 264 + k * 32 + lk];
                ya[i] = __builtin_amdgcn_mfma_f32_16x16x32_bf16(aM, cM, ya[i], 0, 0, 0);
            }
            __builtin_amdgcn_s_setprio(0);
            cH = nH; cM = nM;
        }
        const int col = wave * 16 + lr;
        const float bv = f2a_b[col];
        #pragma unroll
        for (int i = 0; i < 4; ++i)
            #pragma unroll
            for (int rr = 0; rr < 4; ++rr)
                sG[(i * 16 + l4 + rr) * 264 + col] = (bf16)fmaxf(ya[i][rr] + bv, 0.f);
    }
    __syncthreads();   // B5

    // --- fc2b: q_out = y @ f2bw^T + b (waves 0-3, [16,16] tiles)
    if (wave < 4) {
        f32x4 acc[1][1] = {};
        mm_swz<1, 1, 8>(acc, sG + wave * 16 * 264, 264, Wf2b, lane);
        const float bv = f2b_b[lr];
        #pragma unroll
        for (int rr = 0; rr < 4; ++rr)
            q_out[(size_t)(b64 + wave * 16 + l4 + rr) * 16 + lr] = acc[0][0][rr] + bv;
    }
}

// ---------------- launch ----------------
extern "C" void kernel_launch(void* const* d_in, const int* in_sizes, int n_in,
                              void* d_out, int out_size, void* d_ws, size_t ws_size,
                              hipStream_t stream)
{
    const float* in_f   = (const float*)d_in[0];
    const float* hid_f  = (const float*)d_in[1];
    const float* msg_f  = (const float*)d_in[2];
    const int*   topk   = (const int*)d_in[3];
    const float* fc1w_f = (const float*)d_in[4];
    const float* fc1_b  = (const float*)d_in[5];
    const float* wih_f  = (const float*)d_in[6];
    const float* b_ih   = (const float*)d_in[7];
    const float* whh_f  = (const float*)d_in[8];
    const float* b_hh   = (const float*)d_in[9];
    const float* qw_f   = (const float*)d_in[10];
    const float* q_b    = (const float*)d_in[11];
    const float* kw_f   = (const float*)d_in[12];
    // d_in[13] = k_b: softmax-invariant, dropped.
    const float* vw_f   = (const float*)d_in[14];
    const float* v_b    = (const float*)d_in[15];
    const float* f2aw_f = (const float*)d_in[16];
    const float* f2a_b  = (const float*)d_in[17];
    const float* f2bw_f = (const float*)d_in[18];
    const float* f2b_b  = (const float*)d_in[19];

    bf16* ws = (bf16*)d_ws;
    bf16* Wfc1 = ws + OFF_WFC1;
    bf16* WrX  = ws + OFF_WRX;
    bf16* WzX  = ws + OFF_WZX;
    bf16* Wni  = ws + OFF_WNI;
    bf16* WrH  = ws + OFF_WRH;
    bf16* WzH  = ws + OFF_WZH;
    bf16* Wnh  = ws + OFF_WNH;
    bf16* Wq   = ws + OFF_WQ;
    bf16* Wkv  = ws + OFF_WKV;
    bf16* f2aH = ws + OFF_F2AH;
    bf16* f2aM = ws + OFF_F2AM;
    bf16* Wf2b = ws + OFF_WF2B;
    bf16* insw = ws + OFF_INSW;

    float* q_out    = (float*)d_out;                 // [16384,16]
    float* h_out    = q_out + (size_t)ROWS * 16;     // [16384,256]
    float* magg_out = h_out + (size_t)ROWS * 256;    // [16384,256]

    // 1) swizzle weights + 'in' activations to fragment-major bf16
    SwzArgs sa{};
    int s = 0;
    auto add = [&](const float* src, bf16* dst, int N, int K, int ld) {
        sa.seg[s].src = src; sa.seg[s].dst = dst;
        sa.seg[s].items = N * (K >> 3);
        sa.seg[s].k8s = (K == 128) ? 4 : 5;
        sa.seg[s].k32 = K >> 5;
        sa.seg[s].ld = ld; ++s;
    };
    add(fc1w_f,          Wfc1, 256, 128, 128);
    add(wih_f,           WrX,  256, 256, 256);
    add(wih_f +  65536,  WzX,  256, 256, 256);
    add(wih_f + 131072,  Wni,  256, 256, 256);
    add(whh_f,           WrH,  256, 256, 256);
    add(whh_f +  65536,  WzH,  256, 256, 256);
    add(whh_f + 131072,  Wnh,  256, 256, 256);
    add(qw_f,            Wq,    64, 256, 256);
    add(kw_f,            Wkv,   64, 256, 256);
    add(vw_f,            Wkv + 16384, 256, 256, 256);
    add(f2aw_f,          f2aH, 256, 256, 512);
    add(f2aw_f + 256,    f2aM, 256, 256, 512);
    add(f2bw_f,          Wf2b,  16, 256, 256);
    add(in_f,            insw, 16384, 128, 128);
    sa.count = s;
    swz_k<<<512, 256, 0, stream>>>(sa);

    // 2) fully fused per-batch megakernel (256 blocks = 1/CU, 16 waves each)
    mega_k<<<256, 1024, 0, stream>>>(insw, hid_f, msg_f, topk,
                                     Wfc1, fc1_b, WrX, WrH, WzX, WzH, Wni, Wnh,
                                     b_ih, b_hh, Wq, q_b, Wkv, v_b,
                                     f2aH, f2aM, f2a_b, Wf2b, f2b_b,
                                     h_out, magg_out, q_out);
}